// Round 7
// baseline (145.746 us; speedup 1.0000x reference)
//
#include <hip/hip_runtime.h>
#include <hip/hip_bf16.h>

// FixedChannelDP via Toeplitz-GEMM on bf16 MFMA 32x32x16, MR=2 tiles/wave.
// y[p,n] = sum_{k=0}^{512} h[k] x[p,n-k]  ('full' conv), out fp32 [2,NOUT,2].
//
// Grid (1025, 2): one pol per block, BLOCK_OUT=4096 outputs, BLK=128 (2 waves),
// each wave covers 2 adjacent 32x32 tiles (2048 outputs) => 8 MFMAs per
// {2 h-loads + 4 LDS-reads} batch; acc = 64 AGPR, ~55 VGPR -> 4 waves/SIMD.
//
// Mapping (b in [0,34)):
//   D[r][c] += sum_k A_b[r][k] * B_b[k][c],  n = nw + 32r + c
//   A_b[r][k] = x[nw + 32r + k + 16 - 16b]        (8 contiguous -> ds_read_b128)
//   B_b[k][c] = h[16b + c - k - 16]  (0 if OOB)   -> tap covered exactly once
// h table (global ws, L1-resident): hh[tab][R][j] = h[R-24-j], tab 0=hr 1=hi;
//   B-frag row R = 16b + cc - 8*half + 8.  re-part uses (-xi)*hi via v_xor.

#define NSAMP 4194304
#define LTAPS 513
#define NOUT  (NSAMP + LTAPS - 1)   // 4194816

#define BLK       128
#define MR        2
#define TILE      1024
#define WAVE_SPAN (MR * TILE)            // 2048
#define BLOCK_OUT 4096
#define HALO      512
#define XELEMS    (BLOCK_OUT + HALO + 16)   // 4624
#define NB        34
#define HROWS     568
#define NBLKX     ((NOUT + BLOCK_OUT - 1) / BLOCK_OUT)  // 1025

typedef __attribute__((ext_vector_type(8)))  short short8;
typedef __attribute__((ext_vector_type(4)))  short short4v;
typedef __attribute__((ext_vector_type(4)))  int   int4v;
typedef __attribute__((ext_vector_type(16))) float float16v;

// x LDS swizzle: +8 elements (16 B) per 64 -> A-frag b128 reads worst 2-way (free).
__device__ __forceinline__ int xswz(int e) { return e + ((e >> 6) << 3); }
#define XSZ 5208            // xswz(4620)+4 = 5200, padded to 8
#define LS_TILE 1152        // xswz offset of +1024 elements (same e mod 64)

__device__ __forceinline__ short f2b(float f) {
    __bf16 b = (__bf16)f;
    return __builtin_bit_cast(short, b);
}

__global__ __launch_bounds__(256)
void build_h(const float* __restrict__ hr, const float* __restrict__ hi,
             short* __restrict__ hh) {
    int R = blockIdx.x * 256 + threadIdx.x;
    if (R < HROWS) {
        short8 vr, vi;
        #pragma unroll
        for (int j = 0; j < 8; ++j) {
            int idx = R - 24 - j;
            bool ok = (idx >= 0) && (idx < LTAPS);
            vr[j] = f2b(ok ? hr[idx] : 0.0f);
            vi[j] = f2b(ok ? hi[idx] : 0.0f);
        }
        *(short8*)(hh + (size_t)(0 * HROWS + R) * 8) = vr;
        *(short8*)(hh + (size_t)(1 * HROWS + R) * 8) = vi;
    }
}

#define MFMA32(A, B, C) __builtin_amdgcn_mfma_f32_32x32x16_bf16((A), (B), (C), 0, 0, 0)

__device__ __forceinline__ short8 bneg8(short8 v) {
    int4v t = __builtin_bit_cast(int4v, v);
    t ^= (int4v){(int)0x80008000, (int)0x80008000, (int)0x80008000, (int)0x80008000};
    return __builtin_bit_cast(short8, t);
}

// f32x4 -> bf16x4 store into LDS (compiler emits v_cvt + pack)
__device__ __forceinline__ void st_bf16x4(short* dst, float4 v) {
    short4v s = { f2b(v.x), f2b(v.y), f2b(v.z), f2b(v.w) };
    *(short4v*)dst = s;
}

__global__ __launch_bounds__(BLK, 4)
void fir_mfma32m2(const float* __restrict__ txr_all, const float* __restrict__ txi_all,
                  const short* __restrict__ hh, float2* __restrict__ out) {
    const int pol = blockIdx.y;
    const int N0  = blockIdx.x * BLOCK_OUT;
    const int tid = threadIdx.x;

    __shared__ __align__(16) short xr_s[XSZ];
    __shared__ __align__(16) short xi_s[XSZ];

    const float* __restrict__ xr_g = txr_all + (size_t)pol * NSAMP;
    const float* __restrict__ xi_g = txi_all + (size_t)pol * NSAMP;

    // ---- stage x tile [N0-HALO, N0+BLOCK_OUT+16) as bf16, swizzled ----
    const int g0 = N0 - HALO;
    #pragma unroll
    for (int it = 0; it < 10; ++it) {
        int e = (tid + it * BLK) * 4;
        if (e < XELEMS) {
            int g = g0 + e;
            float4 fr, fi;
            if (g >= 0 && g + 3 < NSAMP) {
                fr = *(const float4*)(xr_g + g);
                fi = *(const float4*)(xi_g + g);
            } else {
                int gc0 = min(max(g + 0, 0), NSAMP - 1);
                int gc1 = min(max(g + 1, 0), NSAMP - 1);
                int gc2 = min(max(g + 2, 0), NSAMP - 1);
                int gc3 = min(max(g + 3, 0), NSAMP - 1);
                fr.x = (g + 0 >= 0 && g + 0 < NSAMP) ? xr_g[gc0] : 0.0f;
                fr.y = (g + 1 >= 0 && g + 1 < NSAMP) ? xr_g[gc1] : 0.0f;
                fr.z = (g + 2 >= 0 && g + 2 < NSAMP) ? xr_g[gc2] : 0.0f;
                fr.w = (g + 3 >= 0 && g + 3 < NSAMP) ? xr_g[gc3] : 0.0f;
                fi.x = (g + 0 >= 0 && g + 0 < NSAMP) ? xi_g[gc0] : 0.0f;
                fi.y = (g + 1 >= 0 && g + 1 < NSAMP) ? xi_g[gc1] : 0.0f;
                fi.z = (g + 2 >= 0 && g + 2 < NSAMP) ? xi_g[gc2] : 0.0f;
                fi.w = (g + 3 >= 0 && g + 3 < NSAMP) ? xi_g[gc3] : 0.0f;
            }
            int ls = xswz(e);   // 4-aligned, never crosses a pad boundary
            st_bf16x4(xr_s + ls, fr);
            st_bf16x4(xi_s + ls, fi);
        }
    }
    __syncthreads();

    // ---- MFMA main loop: 2 tiles per wave ----
    const int lane = tid & 63;
    const int wave = tid >> 6;          // 0,1
    const int cc   = lane & 31;         // A row r / B col c / D col
    const int half = lane >> 5;

    float16v acc_re0 = {0.f,0.f,0.f,0.f,0.f,0.f,0.f,0.f,0.f,0.f,0.f,0.f,0.f,0.f,0.f,0.f};
    float16v acc_im0 = acc_re0, acc_re1 = acc_re0, acc_im1 = acc_re0;

    const int    ebase = HALO + wave * WAVE_SPAN + 32 * cc + 8 * half + 16;
    const short* hp0   = hh + (size_t)(cc - 8 * half + 8) * 8;

    for (int b = 0; b < NB; ++b) {
        const short* hp = hp0 + (size_t)(16 * b) * 8;
        short8 fhr = *(const short8*)(hp);
        short8 fhi = *(const short8*)(hp + (size_t)HROWS * 8);
        int ls0 = xswz(ebase - 16 * b);
        short8 fxr0 = *(const short8*)(xr_s + ls0);
        short8 fxi0 = *(const short8*)(xi_s + ls0);
        short8 fxr1 = *(const short8*)(xr_s + ls0 + LS_TILE);
        short8 fxi1 = *(const short8*)(xi_s + ls0 + LS_TILE);
        acc_re0 = MFMA32(fxr0, fhr, acc_re0);
        acc_re0 = MFMA32(bneg8(fxi0), fhi, acc_re0);
        acc_im0 = MFMA32(fxi0, fhr, acc_im0);
        acc_im0 = MFMA32(fxr0, fhi, acc_im0);
        acc_re1 = MFMA32(fxr1, fhr, acc_re1);
        acc_re1 = MFMA32(bneg8(fxi1), fhi, acc_re1);
        acc_im1 = MFMA32(fxi1, fhr, acc_im1);
        acc_im1 = MFMA32(fxr1, fhi, acc_im1);
    }

    // ---- epilogue: D col = lane&31, row = (reg&3) + 8*(reg>>2) + 4*half ----
    float2* __restrict__ op = out + (size_t)pol * NOUT;
    const int nw0 = N0 + wave * WAVE_SPAN;
    if (N0 + BLOCK_OUT <= NOUT) {       // interior: unguarded stores
        #pragma unroll
        for (int m = 0; m < MR; ++m) {
            const float16v& ar = m ? acc_re1 : acc_re0;
            const float16v& ai = m ? acc_im1 : acc_im0;
            #pragma unroll
            for (int v = 0; v < 16; ++v) {
                int row = (v & 3) + 8 * (v >> 2) + 4 * half;
                op[nw0 + m * TILE + 32 * row + cc] = make_float2(ar[v], ai[v]);
            }
        }
    } else {                            // tail block
        #pragma unroll
        for (int m = 0; m < MR; ++m) {
            const float16v& ar = m ? acc_re1 : acc_re0;
            const float16v& ai = m ? acc_im1 : acc_im0;
            #pragma unroll
            for (int v = 0; v < 16; ++v) {
                int row = (v & 3) + 8 * (v >> 2) + 4 * half;
                int n = nw0 + m * TILE + 32 * row + cc;
                if (n < NOUT) op[n] = make_float2(ar[v], ai[v]);
            }
        }
    }
}

extern "C" void kernel_launch(void* const* d_in, const int* in_sizes, int n_in,
                              void* d_out, int out_size, void* d_ws, size_t ws_size,
                              hipStream_t stream) {
    const float* txr = (const float*)d_in[0];
    const float* txi = (const float*)d_in[1];
    const float* hr  = (const float*)d_in[2];
    const float* hi  = (const float*)d_in[3];
    float2* out = (float2*)d_out;
    short* hh = (short*)d_ws;   // 2 * 568 * 8 bf16 = 18 KB

    build_h<<<dim3((HROWS + 255) / 256), 256, 0, stream>>>(hr, hi, hh);

    fir_mfma32m2<<<dim3(NBLKX, 2), BLK, 0, stream>>>(txr, txi, hh, out);
}

// Round 8
// 143.450 us; speedup vs baseline: 1.0160x; 1.0160x over previous
//
#include <hip/hip_runtime.h>
#include <hip/hip_bf16.h>

// FixedChannelDP via Toeplitz-GEMM on bf16 MFMA 32x32x16.
// y[p,n] = sum_{k=0}^{512} h[k] x[p,n-k]  ('full' conv), out fp32 [2,NOUT,2].
//
// Round-5 shape (best: 51 us, 327k conflicts) + 1-deep fragment prefetch:
// the K-loop has NO barrier, so prefetching next iteration's h (global, L1-hot)
// and x (LDS) fragments overlaps their latency with the 4-MFMA batch.
// Block covers n in [N0, N0+2048) for BOTH pols; each wave owns one 32x32-tile
// strip of one pol (waves 0,1 -> pol 0; 2,3 -> pol 1) => acc = 32 AGPR/wave.
//
// Mapping (b in [0,34)):
//   D[r][c] += sum_k A_b[r][k] * B_b[k][c],  n = nw + 32r + c
//   A_b[r][k] = x[nw + 32r + k + 16 - 16b]        (8 contiguous -> ds_read_b128)
//   B_b[k][c] = h[16b + c - k - 16]  (0 if OOB)   -> tap covered exactly once
// h table (global ws, L1-resident): hh[tab][R][j] = h[R-24-j], tab 0=hr 1=hi;
//   B-frag row R = 16b + cc - 8*half + 8.  re-part uses (-xi)*hi via v_xor.

#define NSAMP 4194304
#define LTAPS 513
#define NOUT  (NSAMP + LTAPS - 1)   // 4194816

#define BLK       256
#define WAVE_OUT  1024                  // one 32x32 D tile strip per wave
#define BLOCK_OUT 2048                  // per pol
#define HALO      512
#define XELEMS    (BLOCK_OUT + HALO + 16)   // 2576
#define NB        34
#define HROWS     568
#define NBLK      ((NOUT + BLOCK_OUT - 1) / BLOCK_OUT)  // 2049

typedef __attribute__((ext_vector_type(8)))  short short8;
typedef __attribute__((ext_vector_type(4)))  short short4v;
typedef __attribute__((ext_vector_type(4)))  int   int4v;
typedef __attribute__((ext_vector_type(16))) float float16v;

// x LDS swizzle: +8 elements (16 B) per 32 -> A-frag b128 reads hit all 32 banks
// (lane stride 80 B = 20 banks, gcd(20,32)=4, 8-lane groups tile the banks).
__device__ __forceinline__ int xswz(int e) { return e + ((e >> 5) << 3); }
#define XSZ 3224   // xswz(2572)+4 = 3216, padded to 8-short multiple

__device__ __forceinline__ short f2b(float f) {
    __bf16 b = (__bf16)f;
    return __builtin_bit_cast(short, b);
}

__global__ __launch_bounds__(256)
void build_h(const float* __restrict__ hr, const float* __restrict__ hi,
             short* __restrict__ hh) {
    int R = blockIdx.x * 256 + threadIdx.x;
    if (R < HROWS) {
        short8 vr, vi;
        #pragma unroll
        for (int j = 0; j < 8; ++j) {
            int idx = R - 24 - j;
            bool ok = (idx >= 0) && (idx < LTAPS);
            vr[j] = f2b(ok ? hr[idx] : 0.0f);
            vi[j] = f2b(ok ? hi[idx] : 0.0f);
        }
        *(short8*)(hh + (size_t)(0 * HROWS + R) * 8) = vr;
        *(short8*)(hh + (size_t)(1 * HROWS + R) * 8) = vi;
    }
}

#define MFMA32(A, B, C) __builtin_amdgcn_mfma_f32_32x32x16_bf16((A), (B), (C), 0, 0, 0)

__device__ __forceinline__ short8 bneg8(short8 v) {
    int4v t = __builtin_bit_cast(int4v, v);
    t ^= (int4v){(int)0x80008000, (int)0x80008000, (int)0x80008000, (int)0x80008000};
    return __builtin_bit_cast(short8, t);
}

__global__ __launch_bounds__(BLK)
void fir_mfma32p(const float* __restrict__ txr_all, const float* __restrict__ txi_all,
                 const short* __restrict__ hh, float2* __restrict__ out) {
    const int N0  = blockIdx.x * BLOCK_OUT;
    const int tid = threadIdx.x;

    __shared__ __align__(16) short xr_s[2][XSZ];
    __shared__ __align__(16) short xi_s[2][XSZ];

    // ---- stage x tiles (both pols) [N0-HALO, N0+BLOCK_OUT+16) as bf16, swizzled ----
    #pragma unroll
    for (int p = 0; p < 2; ++p) {
        const float* __restrict__ xr_g = txr_all + (size_t)p * NSAMP;
        const float* __restrict__ xi_g = txi_all + (size_t)p * NSAMP;
        #pragma unroll
        for (int it = 0; it < 3; ++it) {
            int e = (tid + it * BLK) * 4;
            if (e < XELEMS) {
                int g = N0 - HALO + e;
                float4 fr, fi;
                if (g >= 0 && g + 3 < NSAMP) {
                    fr = *(const float4*)(xr_g + g);
                    fi = *(const float4*)(xi_g + g);
                } else {
                    int gc0 = min(max(g + 0, 0), NSAMP - 1);
                    int gc1 = min(max(g + 1, 0), NSAMP - 1);
                    int gc2 = min(max(g + 2, 0), NSAMP - 1);
                    int gc3 = min(max(g + 3, 0), NSAMP - 1);
                    fr.x = (g + 0 >= 0 && g + 0 < NSAMP) ? xr_g[gc0] : 0.0f;
                    fr.y = (g + 1 >= 0 && g + 1 < NSAMP) ? xr_g[gc1] : 0.0f;
                    fr.z = (g + 2 >= 0 && g + 2 < NSAMP) ? xr_g[gc2] : 0.0f;
                    fr.w = (g + 3 >= 0 && g + 3 < NSAMP) ? xr_g[gc3] : 0.0f;
                    fi.x = (g + 0 >= 0 && g + 0 < NSAMP) ? xi_g[gc0] : 0.0f;
                    fi.y = (g + 1 >= 0 && g + 1 < NSAMP) ? xi_g[gc1] : 0.0f;
                    fi.z = (g + 2 >= 0 && g + 2 < NSAMP) ? xi_g[gc2] : 0.0f;
                    fi.w = (g + 3 >= 0 && g + 3 < NSAMP) ? xi_g[gc3] : 0.0f;
                }
                int ls = xswz(e);   // 4-aligned, never crosses a pad boundary
                short4v vr = { f2b(fr.x), f2b(fr.y), f2b(fr.z), f2b(fr.w) };
                short4v vi = { f2b(fi.x), f2b(fi.y), f2b(fi.z), f2b(fi.w) };
                *(short4v*)(&xr_s[p][ls]) = vr;
                *(short4v*)(&xi_s[p][ls]) = vi;
            }
        }
    }
    __syncthreads();

    // ---- MFMA main loop: one 32x32 tile strip per wave, one pol per wave ----
    const int lane  = tid & 63;
    const int wave  = tid >> 6;
    const int pol   = wave >> 1;    // waves 0,1 -> pol 0; 2,3 -> pol 1
    const int strip = wave & 1;     // n-offset strip within block
    const int cc    = lane & 31;    // A row r / B col c / D col
    const int half  = lane >> 5;

    float16v acc_re = {0.f,0.f,0.f,0.f,0.f,0.f,0.f,0.f,0.f,0.f,0.f,0.f,0.f,0.f,0.f,0.f};
    float16v acc_im = acc_re;

    const int    ebase = HALO + strip * WAVE_OUT + 32 * cc + 8 * half + 16;
    const short* hp0   = hh + (size_t)(cc - 8 * half + 8) * 8;
    const short* xrp   = xr_s[pol];
    const short* xip   = xi_s[pol];

    // prefetch b = 0
    short8 fhr = *(const short8*)(hp0);
    short8 fhi = *(const short8*)(hp0 + (size_t)HROWS * 8);
    int ls0 = xswz(ebase);
    short8 fxr = *(const short8*)(xrp + ls0);
    short8 fxi = *(const short8*)(xip + ls0);

    #pragma unroll 2
    for (int b = 0; b < NB; ++b) {
        // issue next iteration's loads (clamped at the end; result unused)
        int bn = (b + 1 < NB) ? (b + 1) : b;
        const short* hpn = hp0 + (size_t)(16 * bn) * 8;
        short8 nhr = *(const short8*)(hpn);
        short8 nhi = *(const short8*)(hpn + (size_t)HROWS * 8);
        int lsn = xswz(ebase - 16 * bn);
        short8 nxr = *(const short8*)(xrp + lsn);
        short8 nxi = *(const short8*)(xip + lsn);

        acc_re = MFMA32(fxr,        fhr, acc_re);
        acc_re = MFMA32(bneg8(fxi), fhi, acc_re);
        acc_im = MFMA32(fxi,        fhr, acc_im);
        acc_im = MFMA32(fxr,        fhi, acc_im);

        fhr = nhr; fhi = nhi; fxr = nxr; fxi = nxi;
    }

    // ---- epilogue: D col = lane&31, row = (reg&3) + 8*(reg>>2) + 4*half ----
    float2* __restrict__ op = out + (size_t)pol * NOUT;
    const int nw = N0 + strip * WAVE_OUT;
    #pragma unroll
    for (int v = 0; v < 16; ++v) {
        int row = (v & 3) + 8 * (v >> 2) + 4 * half;
        int n = nw + 32 * row + cc;
        if (n < NOUT) op[n] = make_float2(acc_re[v], acc_im[v]);
    }
}

extern "C" void kernel_launch(void* const* d_in, const int* in_sizes, int n_in,
                              void* d_out, int out_size, void* d_ws, size_t ws_size,
                              hipStream_t stream) {
    const float* txr = (const float*)d_in[0];
    const float* txi = (const float*)d_in[1];
    const float* hr  = (const float*)d_in[2];
    const float* hi  = (const float*)d_in[3];
    float2* out = (float2*)d_out;
    short* hh = (short*)d_ws;   // 2 * 568 * 8 bf16 = 18 KB

    build_h<<<dim3((HROWS + 255) / 256), 256, 0, stream>>>(hr, hi, hh);

    fir_mfma32p<<<dim3(NBLK), BLK, 0, stream>>>(txr, txi, hh, out);
}